// Round 13
// baseline (443.703 us; speedup 1.0000x reference)
//
#include <hip/hip_runtime.h>
#include <hip/hip_fp16.h>
#include <cmath>
#include <cstdint>

#define NU 100000
#define NI 50000
#define NALL 150000
#define DIM 64
#define NE 4800000

#define BSH 7                 // bucket = row >> 7  (128 rows/bucket)
#define BROWS 128
#define NBUCK ((NALL + BROWS - 1) / BROWS)   // 1172
#define SBT 512               // sort-kernel block threads
#define EPT 8                 // edges per thread (512 * 8 = 4096 per block)
#define CHUNK (SBT * EPT)     // 4096 edges per binning block
#define COLMASK 0x3FFFF       // 18 bits, NALL < 2^18
#define BCAP 4608             // bucket capacity for staged sort (mean 4096 + 8 sigma)
#define SPT 9                 // staged regs per thread in bucket_sort (512*9=4608)

// ---------------- CSR build (proven path, unchanged) ----------------

__global__ __launch_bounds__(SBT) void bucket_hist_kernel(
        const int* __restrict__ rows, int* __restrict__ bcnt) {
    __shared__ int h[NBUCK];
    for (int i = threadIdx.x; i < NBUCK; i += SBT) h[i] = 0;
    __syncthreads();
    int base = blockIdx.x * CHUNK;
    #pragma unroll
    for (int i = 0; i < EPT; i++) {
        int e = base + threadIdx.x + i * SBT;
        if (e < NE) atomicAdd(&h[rows[e] >> BSH], 1);
    }
    __syncthreads();
    for (int i = threadIdx.x; i < NBUCK; i += SBT)
        if (h[i]) atomicAdd(&bcnt[i], h[i]);
}

__global__ void bucket_scan_kernel(const int* __restrict__ bcnt, int* __restrict__ bptr) {
    __shared__ int s[1024];
    int t = threadIdx.x;
    const int chunk = (NBUCK + 1023) / 1024;   // 2
    int lo = t * chunk, hi = lo + chunk;
    if (hi > NBUCK) hi = NBUCK;
    int sum = 0;
    for (int i = lo; i < hi; ++i) sum += bcnt[i];
    s[t] = sum;
    __syncthreads();
    for (int off = 1; off < 1024; off <<= 1) {
        int v = (t >= off) ? s[t - off] : 0;
        __syncthreads();
        s[t] += v;
        __syncthreads();
    }
    int run = s[t] - sum;
    for (int i = lo; i < hi; ++i) { bptr[i] = run; run += bcnt[i]; }
    if (t == 1023) bptr[NBUCK] = s[1023];
}

__global__ __launch_bounds__(SBT, 6) void binned_scatter_kernel(
        const int* __restrict__ rows, const int* __restrict__ cols,
        const float* __restrict__ vals, const int* __restrict__ bptr,
        int* __restrict__ bfill, int2* __restrict__ tmp) {
    __shared__ int2 eLDS[CHUNK];             // 32 KB
    __shared__ unsigned short bLDS[CHUNK];   // 8 KB bucket-id sidecar
    __shared__ int lcnt[NBUCK];              // ranks, then writeout delta
    __shared__ int lofs[NBUCK + 1];
    __shared__ int psum[SBT];
    int t = threadIdx.x;
    int base = blockIdx.x * CHUNK;
    int cnt = NE - base; if (cnt > CHUNK) cnt = CHUNK;
    for (int i = t; i < NBUCK; i += SBT) lcnt[i] = 0;
    __syncthreads();
    int2 ed[EPT]; int mcb[EPT]; int mrk[EPT];
    #pragma unroll
    for (int k = 0; k < EPT; k++) {
        int p = t + k * SBT;
        mcb[k] = -1;
        if (p < cnt) {
            int e = base + p;
            int r = rows[e];
            int cb = r >> BSH;
            mcb[k] = cb;
            mrk[k] = atomicAdd(&lcnt[cb], 1);
            ed[k] = make_int2(((r & (BROWS - 1)) << 18) | cols[e], __float_as_int(vals[e]));
        }
    }
    __syncthreads();
    const int cpt = (NBUCK + SBT - 1) / SBT;   // 3
    int lo = t * cpt, hi = lo + cpt;
    if (lo > NBUCK) lo = NBUCK;
    if (hi > NBUCK) hi = NBUCK;
    int s = 0;
    for (int i = lo; i < hi; ++i) s += lcnt[i];
    psum[t] = s;
    __syncthreads();
    for (int off = 1; off < SBT; off <<= 1) {
        int v = (t >= off) ? psum[t - off] : 0;
        __syncthreads();
        psum[t] += v;
        __syncthreads();
    }
    int run = psum[t] - s;
    for (int i = lo; i < hi; ++i) { lofs[i] = run; run += lcnt[i]; }
    if (t == SBT - 1) lofs[NBUCK] = cnt;
    __syncthreads();
    for (int i = t; i < NBUCK; i += SBT) {
        int c = lcnt[i];
        int g = c ? atomicAdd(&bfill[i], c) : 0;
        lcnt[i] = bptr[i] + g - lofs[i];
    }
    #pragma unroll
    for (int k = 0; k < EPT; k++)
        if (mcb[k] >= 0) {
            int pos = lofs[mcb[k]] + mrk[k];
            eLDS[pos] = ed[k];
            bLDS[pos] = (unsigned short)mcb[k];
        }
    __syncthreads();
    for (int p = t; p < cnt; p += SBT)
        tmp[lcnt[bLDS[p]] + p] = eLDS[p];
}

__global__ __launch_bounds__(SBT, 6) void bucket_sort_kernel(
        const int* __restrict__ bptr, const int2* __restrict__ tmp,
        int2* __restrict__ sedges, int* __restrict__ row_ptr) {
    __shared__ int2 eLDS[BCAP];           // 36.9 KB
    __shared__ int h[BROWS], sc[BROWS], f[BROWS];
    int b = blockIdx.x, t = threadIdx.x;
    int s0 = bptr[b], s1 = bptr[b + 1];
    int cnt = s1 - s0;
    if (t < BROWS) { h[t] = 0; f[t] = 0; }
    if (b == NBUCK - 1 && t == 0) row_ptr[NALL] = s1;
    __syncthreads();
    if (cnt <= BCAP) {
        int2 ed[SPT]; int mrl[SPT]; int mrk[SPT];
        #pragma unroll
        for (int k = 0; k < SPT; k++) {
            int p = t + k * SBT;
            mrl[k] = -1;
            if (p < cnt) {
                int2 E = tmp[s0 + p];
                int rl = E.x >> 18;
                mrl[k] = rl;
                mrk[k] = atomicAdd(&h[rl], 1);
                ed[k] = E;
            }
        }
        __syncthreads();
        if (t < BROWS) sc[t] = h[t];
        __syncthreads();
        for (int off = 1; off < BROWS; off <<= 1) {
            int v = 0;
            if (t < BROWS && t >= off) v = sc[t - off];
            __syncthreads();
            if (t < BROWS) sc[t] += v;
            __syncthreads();
        }
        if (t < BROWS) {
            int row = b * BROWS + t;
            if (row < NALL) row_ptr[row] = s0 + sc[t] - h[t];
        }
        __syncthreads();
        #pragma unroll
        for (int k = 0; k < SPT; k++)
            if (mrl[k] >= 0) eLDS[sc[mrl[k]] - h[mrl[k]] + mrk[k]] = ed[k];
        __syncthreads();
        for (int p = t; p < cnt; p += SBT) sedges[s0 + p] = eLDS[p];
    } else {
        for (int i = s0 + t; i < s1; i += SBT) atomicAdd(&h[tmp[i].x >> 18], 1);
        __syncthreads();
        if (t < BROWS) sc[t] = h[t];
        __syncthreads();
        for (int off = 1; off < BROWS; off <<= 1) {
            int v = 0;
            if (t < BROWS && t >= off) v = sc[t - off];
            __syncthreads();
            if (t < BROWS) sc[t] += v;
            __syncthreads();
        }
        if (t < BROWS) {
            int row = b * BROWS + t;
            if (row < NALL) row_ptr[row] = s0 + sc[t] - h[t];
        }
        __syncthreads();
        for (int i = s0 + t; i < s1; i += SBT) {
            int2 E = tmp[i];
            int rl = E.x >> 18;
            int r = atomicAdd(&f[rl], 1);
            sedges[s0 + sc[rl] - h[rl] + r] = E;
        }
    }
}

// ---------------- embedding passes ----------------

__global__ void concat_init_kernel(const float4* __restrict__ u4, const float4* __restrict__ it4,
                                   float4* __restrict__ w0, uint2* __restrict__ w0h,
                                   float4* __restrict__ out4) {
    int idx = blockIdx.x * blockDim.x + threadIdx.x;
    const int total4 = NALL * 16;
    if (idx >= total4) return;
    const int nu4 = NU * 16;
    float4 v = (idx < nu4) ? u4[idx] : it4[idx - nu4];
    if (w0) w0[idx] = v;
    if (w0h) {
        __half2 a = __floats2half2_rn(v.x, v.y), b = __floats2half2_rn(v.z, v.w);
        w0h[idx] = make_uint2(*(unsigned*)&a, *(unsigned*)&b);
    }
    if (out4) {
        int row = idx >> 4, q = idx & 15;
        out4[(size_t)row * 32 + q] = v;
    }
}

// Mixed-precision FMA: acc(f32) += f16(lo/hi of x) * v(f32) in ONE VOP3P instruction.
#define FMAMIX_LO(a, x, s) asm("v_fma_mix_f32 %0, %1, %2, %0 op_sel:[0,0,0] op_sel_hi:[1,0,0]" : "+v"(a) : "v"(x), "v"(s))
#define FMAMIX_HI(a, x, s) asm("v_fma_mix_f32 %0, %1, %2, %0 op_sel:[1,0,0] op_sel_hi:[1,0,0]" : "+v"(a) : "v"(x), "v"(s))

__device__ __forceinline__ void fma_mix8(float* acc, uint4 p, float v) {
    FMAMIX_LO(acc[0], p.x, v); FMAMIX_HI(acc[1], p.x, v);
    FMAMIX_LO(acc[2], p.y, v); FMAMIX_HI(acc[3], p.y, v);
    FMAMIX_LO(acc[4], p.z, v); FMAMIX_HI(acc[5], p.z, v);
    FMAMIX_LO(acc[6], p.w, v); FMAMIX_HI(acc[7], p.w, v);
}

// float4 pair (dims [l8*8, l8*8+8)) of row `wid` from the concatenated fp32 inputs.
__device__ __forceinline__ void load_pair_e0(const float4* __restrict__ u4,
                                             const float4* __restrict__ it4,
                                             int wid, int l8, float4& a, float4& b) {
    const float4* q = (wid < NU) ? (u4 + (size_t)wid * 16 + l8 * 2)
                                 : (it4 + (size_t)(wid - NU) * 16 + l8 * 2);
    a = q[0]; b = q[1];
}

// same pair from an fp16 mirror (one uint4 = 8 halves).
__device__ __forceinline__ void load_pair_h(const __half* __restrict__ h,
                                            int wid, int l8, float4& a, float4& b) {
    uint4 p = ((const uint4*)h)[(size_t)wid * 8 + l8];
    __half2* hp = (__half2*)&p;
    float2 f0 = __half22float2(hp[0]);
    float2 f1 = __half22float2(hp[1]);
    float2 f2 = __half22float2(hp[2]);
    float2 f3 = __half22float2(hp[3]);
    a = make_float4(f0.x, f0.y, f1.x, f1.y);
    b = make_float4(f2.x, f2.y, f3.x, f3.y);
}

__device__ __forceinline__ uint4 pack_h8(float4 a, float4 b) {
    __half2 h0 = __floats2half2_rn(a.x, a.y);
    __half2 h1 = __floats2half2_rn(a.z, a.w);
    __half2 h2 = __floats2half2_rn(b.x, b.y);
    __half2 h3 = __floats2half2_rn(b.z, b.w);
    uint4 ph;
    ph.x = *(unsigned*)&h0; ph.y = *(unsigned*)&h1;
    ph.z = *(unsigned*)&h2; ph.w = *(unsigned*)&h3;
    return ph;
}

// Contiguous-4 edge blocks per 8-lane group: group g handles edges {s+32*it+4g .. +3}.
// Two dwordx4 loads fetch 4 edge descriptors; 4 gathers stay in flight; only the
// 3 trailing vals need zero-predication. Reads ≤3 edges past row end hit the next
// row (val masked) or the 4-entry zeroed slack after sedges (last row).
__device__ __forceinline__ void spmm_row_acc(const int* __restrict__ row_ptr,
                                             const int2* __restrict__ sedges,
                                             const uint4* __restrict__ xv,
                                             int wid, int g, int l8, float* acc) {
    int s = row_ptr[wid], e = row_ptr[wid + 1];
    for (int j = s + 4 * g; j < e; j += 32) {
        const int4* p2 = (const int4*)(sedges + j);   // 8B-aligned; dwordx4 ok
        int4 eA = p2[0];                               // edges j, j+1
        int4 eB = p2[1];                               // edges j+2, j+3
        uint4 q0 = xv[(size_t)(eA.x & COLMASK) * 8 + l8];
        uint4 q1 = xv[(size_t)(eA.z & COLMASK) * 8 + l8];
        uint4 q2 = xv[(size_t)(eB.x & COLMASK) * 8 + l8];
        uint4 q3 = xv[(size_t)(eB.z & COLMASK) * 8 + l8];
        float v0 = __int_as_float(eA.y);
        float v1 = (j + 1 < e) ? __int_as_float(eA.w) : 0.f;
        float v2 = (j + 2 < e) ? __int_as_float(eB.y) : 0.f;
        float v3 = (j + 3 < e) ? __int_as_float(eB.w) : 0.f;
        fma_mix8(acc, q0, v0);
        fma_mix8(acc, q1, v1);
        fma_mix8(acc, q2, v2);
        fma_mix8(acc, q3, v3);
    }
    #pragma unroll
    for (int off = 8; off < 64; off <<= 1) {
        #pragma unroll
        for (int j = 0; j < 8; j++) acc[j] += __shfl_xor(acc[j], off);
    }
}

// Passes 1..N-1: ek = t1*spmm(x) + t2*ekm1 - t3*ekm2; result lives ONLY as fp16 mirror.
__global__ __launch_bounds__(256) void spmm8_combine_f16_kernel(
        const int* __restrict__ row_ptr, const int2* __restrict__ sedges,
        const __half* __restrict__ xh,
        const __half* __restrict__ em1h, int em1_embed,
        const __half* __restrict__ em2h, int em2_embed,
        const float4* __restrict__ u4, const float4* __restrict__ it4,
        float t1, float t2, float t3,
        __half* __restrict__ ekh_out) {
    int wid = (blockIdx.x * blockDim.x + threadIdx.x) >> 6;
    if (wid >= NALL) return;
    int lane = threadIdx.x & 63;
    int g = lane >> 3, l8 = lane & 7;
    float acc[8];
    #pragma unroll
    for (int j = 0; j < 8; j++) acc[j] = 0.f;
    spmm_row_acc(row_ptr, sedges, (const uint4*)xh, wid, g, l8, acc);
    if (g == 0) {
        float4 ea, eb;
        ea.x = t1 * acc[0]; ea.y = t1 * acc[1]; ea.z = t1 * acc[2]; ea.w = t1 * acc[3];
        eb.x = t1 * acc[4]; eb.y = t1 * acc[5]; eb.z = t1 * acc[6]; eb.w = t1 * acc[7];
        if (t2 != 0.f) {
            float4 m1a, m1b;
            if (em1_embed) load_pair_e0(u4, it4, wid, l8, m1a, m1b);
            else           load_pair_h(em1h, wid, l8, m1a, m1b);
            ea.x += t2 * m1a.x; ea.y += t2 * m1a.y; ea.z += t2 * m1a.z; ea.w += t2 * m1a.w;
            eb.x += t2 * m1b.x; eb.y += t2 * m1b.y; eb.z += t2 * m1b.z; eb.w += t2 * m1b.w;
        }
        if (t3 != 0.f) {
            float4 m2a, m2b;
            if (em2_embed) load_pair_e0(u4, it4, wid, l8, m2a, m2b);
            else           load_pair_h(em2h, wid, l8, m2a, m2b);
            ea.x -= t3 * m2a.x; ea.y -= t3 * m2a.y; ea.z -= t3 * m2a.z; ea.w -= t3 * m2a.w;
            eb.x -= t3 * m2b.x; eb.y -= t3 * m2b.y; eb.z -= t3 * m2b.z; eb.w -= t3 * m2b.w;
        }
        ((uint4*)ekh_out)[(size_t)wid * 8 + l8] = pack_h8(ea, eb);
    }
}

// Final pass fused with finalize: e3 = t1*spmm(e2) + t2*e2 - t3*e1;
// bs = (e0+e1+e2+e3)/4; bp = tanh(0.1*e0 - bs). e0 from fp32 inputs; e1,e2 fp16.
__global__ __launch_bounds__(256) void spmm8_final_kernel(
        const int* __restrict__ row_ptr, const int2* __restrict__ sedges,
        const __half* __restrict__ xh,
        const __half* __restrict__ e1h, const __half* __restrict__ e2h,
        const float4* __restrict__ u4, const float4* __restrict__ it4,
        float t1, float t2, float t3,
        float4* __restrict__ out4) {
    int wid = (blockIdx.x * blockDim.x + threadIdx.x) >> 6;
    if (wid >= NALL) return;
    int lane = threadIdx.x & 63;
    int g = lane >> 3, l8 = lane & 7;
    float acc[8];
    #pragma unroll
    for (int j = 0; j < 8; j++) acc[j] = 0.f;
    spmm_row_acc(row_ptr, sedges, (const uint4*)xh, wid, g, l8, acc);
    if (g == 0) {
        float4 e0a, e0b, e1a, e1b, e2a, e2b;
        load_pair_e0(u4, it4, wid, l8, e0a, e0b);
        load_pair_h(e1h, wid, l8, e1a, e1b);
        load_pair_h(e2h, wid, l8, e2a, e2b);
        float4 e3a, e3b;
        e3a.x = t1 * acc[0] + t2 * e2a.x - t3 * e1a.x;
        e3a.y = t1 * acc[1] + t2 * e2a.y - t3 * e1a.y;
        e3a.z = t1 * acc[2] + t2 * e2a.z - t3 * e1a.z;
        e3a.w = t1 * acc[3] + t2 * e2a.w - t3 * e1a.w;
        e3b.x = t1 * acc[4] + t2 * e2b.x - t3 * e1b.x;
        e3b.y = t1 * acc[5] + t2 * e2b.y - t3 * e1b.y;
        e3b.z = t1 * acc[6] + t2 * e2b.z - t3 * e1b.z;
        e3b.w = t1 * acc[7] + t2 * e2b.w - t3 * e1b.w;
        float4 bsa, bsb, bpa, bpb;
        bsa.x = 0.25f * (e0a.x + e1a.x + e2a.x + e3a.x);
        bsa.y = 0.25f * (e0a.y + e1a.y + e2a.y + e3a.y);
        bsa.z = 0.25f * (e0a.z + e1a.z + e2a.z + e3a.z);
        bsa.w = 0.25f * (e0a.w + e1a.w + e2a.w + e3a.w);
        bsb.x = 0.25f * (e0b.x + e1b.x + e2b.x + e3b.x);
        bsb.y = 0.25f * (e0b.y + e1b.y + e2b.y + e3b.y);
        bsb.z = 0.25f * (e0b.z + e1b.z + e2b.z + e3b.z);
        bsb.w = 0.25f * (e0b.w + e1b.w + e2b.w + e3b.w);
        bpa.x = tanhf(0.1f * e0a.x - bsa.x);
        bpa.y = tanhf(0.1f * e0a.y - bsa.y);
        bpa.z = tanhf(0.1f * e0a.z - bsa.z);
        bpa.w = tanhf(0.1f * e0a.w - bsa.w);
        bpb.x = tanhf(0.1f * e0b.x - bsb.x);
        bpb.y = tanhf(0.1f * e0b.y - bsb.y);
        bpb.z = tanhf(0.1f * e0b.z - bsb.z);
        bpb.w = tanhf(0.1f * e0b.w - bsb.w);
        size_t ob = (size_t)wid * 32 + l8 * 2;
        out4[ob] = bsa;
        out4[ob + 1] = bsb;
        out4[ob + 16] = bpa;
        out4[ob + 17] = bpb;
    }
}

// ---------------- fallback kernels (ws-constrained paths) ----------------

__global__ void spmm_combine_kernel(const int* __restrict__ row_ptr,
                                    const int2* __restrict__ sedges,
                                    const float* __restrict__ x,
                                    const float* __restrict__ ekm1,
                                    const float* __restrict__ ekm2,
                                    float t1, float t2, float t3,
                                    float* __restrict__ ek_out,
                                    float* __restrict__ out) {
    int wid = (blockIdx.x * blockDim.x + threadIdx.x) >> 6;
    if (wid >= NALL) return;
    int lane = threadIdx.x & 63;
    int s = row_ptr[wid], e = row_ptr[wid + 1];
    float acc = 0.f;
    int i = s;
    for (; i + 4 <= e; i += 4) {
        int2 ea = sedges[i], eb = sedges[i + 1], ec = sedges[i + 2], ed = sedges[i + 3];
        acc += __int_as_float(ea.y) * x[(size_t)(ea.x & COLMASK) * DIM + lane];
        acc += __int_as_float(eb.y) * x[(size_t)(eb.x & COLMASK) * DIM + lane];
        acc += __int_as_float(ec.y) * x[(size_t)(ec.x & COLMASK) * DIM + lane];
        acc += __int_as_float(ed.y) * x[(size_t)(ed.x & COLMASK) * DIM + lane];
    }
    for (; i < e; ++i) {
        int2 ed = sedges[i];
        acc += __int_as_float(ed.y) * x[(size_t)(ed.x & COLMASK) * DIM + lane];
    }
    size_t o = (size_t)wid * DIM + lane;
    float ek = t1 * acc + t2 * ekm1[o] - t3 * ekm2[o];
    ek_out[o] = ek;
    out[(size_t)wid * 128 + lane] += ek;
}

__global__ void finalize_kernel(const float* __restrict__ u, const float* __restrict__ it,
                                float* __restrict__ out) {
    int idx = blockIdx.x * blockDim.x + threadIdx.x;
    const int total = NALL * DIM;
    if (idx >= total) return;
    const int nue = NU * DIM;
    float v = (idx < nue) ? u[idx] : it[idx - nue];
    int row = idx >> 6, d = idx & 63;
    size_t o = (size_t)row * 128 + d;
    float bs = out[o] * 0.25f;
    float bp = tanhf(0.1f * v - bs);
    out[o] = bs;
    out[o + DIM] = bp;
}

__global__ void spmm_atomic_kernel(const int* __restrict__ rows, const int* __restrict__ cols,
                                   const float* __restrict__ vals, const float* __restrict__ x,
                                   float* __restrict__ y) {
    int gid = blockIdx.x * blockDim.x + threadIdx.x;
    int e = gid >> 6;
    if (e >= NE) return;
    int lane = threadIdx.x & 63;
    atomicAdd(&y[(size_t)rows[e] * DIM + lane], vals[e] * x[(size_t)cols[e] * DIM + lane]);
}

__global__ void combine3_kernel(float* __restrict__ t, const float* __restrict__ ekm1,
                                const float* __restrict__ ekm2, float t1, float t2, float t3,
                                float* __restrict__ out) {
    int idx = blockIdx.x * blockDim.x + threadIdx.x;
    const int total = NALL * DIM;
    if (idx >= total) return;
    float ek = t1 * t[idx] + t2 * ekm1[idx] - t3 * ekm2[idx];
    t[idx] = ek;
    int row = idx >> 6, d = idx & 63;
    out[(size_t)row * 128 + d] += ek;
}

// ---------------- launch ----------------

extern "C" void kernel_launch(void* const* d_in, const int* in_sizes, int n_in,
                              void* d_out, int out_size, void* d_ws, size_t ws_size,
                              hipStream_t stream) {
    const float* user_emb = (const float*)d_in[0];
    const float* item_emb = (const float*)d_in[1];
    const int*   rows     = (const int*)d_in[2];
    const int*   cols     = (const int*)d_in[3];
    const float* vals     = (const float*)d_in[4];
    float* out = (float*)d_out;

    const size_t nbuf = (size_t)NALL * DIM;            // 9.6M elements
    float* W0 = (float*)d_ws;
    float* W1 = W0 + nbuf;
    float* W2 = W1 + nbuf;
    int2*  tmp     = (int2*)W1;                        // alias: dead before propagation
    int2*  sedges  = (int2*)(W2 + nbuf);               // NE * 8 B (+ 4-edge zero slack)
    int*   row_ptr = (int*)(sedges + NE + 4);          // NALL+1
    int*   bcnt    = row_ptr + (NALL + 1);             // NBUCK
    int*   bptr    = bcnt + NBUCK;                     // NBUCK+1
    int*   bfill   = bptr + (NBUCK + 1);               // NBUCK
    char*  pHA     = (char*)(bfill + NBUCK);
    pHA = (char*)(((uintptr_t)pHA + 255) & ~(uintptr_t)255);   // 256B-align mirrors
    __half* HA     = (__half*)pHA;                     // fp16 e0 mirror
    __half* HB     = HA + nbuf;                        // fp16 e1 mirror
    __half* HC     = HB + nbuf;                        // fp16 e2 mirror
    size_t need_basic = (size_t)((char*)HA - (char*)d_ws);
    size_t need_full  = (size_t)((char*)(HC + nbuf) - (char*)d_ws);

    // Jacobi coefficients (A=B=1 here, computed generically)
    const double A = 1.0, B = 1.0, ab = A + B;
    float c0 = (float)((A - B) / 2.0);
    float c1 = (float)((A + B) / 2.0);
    float th1[4], th2[4], th3[4];
    for (int k = 2; k <= 3; k++) {
        th1[k] = (float)((2.0*k+ab)*(2.0*k+ab-1.0)/((k+ab)*2.0*k));
        th2[k] = (float)((2.0*k+ab-1.0)*(A*A-B*B)/((2.0*k+ab-2.0)*(k+ab)*2.0*k));
        th3[k] = (float)((k+A-1.0)*(k+B-1.0)*(2.0*k+ab)/(k*(ab+k)*(2.0*k+ab-2.0)));
    }

    const int total = NALL * DIM;
    const int total4 = NALL * 16;
    dim3 blk(256);
    dim3 sblk(SBT);
    dim3 grdE((total + 255) / 256);
    dim3 grd4((total4 + 255) / 256);
    dim3 grdBin((NE + CHUNK - 1) / CHUNK);             // 1172
    dim3 grdBuck(NBUCK);                               // 1172
    dim3 grdRow((NALL * 64 + 255) / 256);              // wave-per-row

    const float4* u4  = (const float4*)user_emb;
    const float4* it4 = (const float4*)item_emb;

    if (ws_size >= need_basic) {
        // ---- edge sort ----
        hipMemsetAsync(bcnt, 0, NBUCK * sizeof(int), stream);
        hipMemsetAsync(bfill, 0, NBUCK * sizeof(int), stream);
        hipMemsetAsync(sedges + NE, 0, 4 * sizeof(int2), stream);   // gather-slack
        bucket_hist_kernel<<<grdBin, sblk, 0, stream>>>(rows, bcnt);
        bucket_scan_kernel<<<1, 1024, 0, stream>>>(bcnt, bptr);
        binned_scatter_kernel<<<grdBin, sblk, 0, stream>>>(rows, cols, vals, bptr, bfill, tmp);
        bucket_sort_kernel<<<grdBuck, sblk, 0, stream>>>(bptr, tmp, sedges, row_ptr);

        if (ws_size >= need_full) {
            // ---- fp16-mirror-only pipeline ----
            concat_init_kernel<<<grd4, blk, 0, stream>>>(u4, it4, nullptr, (uint2*)HA, nullptr);
            // e1 = c1*spmm(e0) + c0*e0            -> HB
            spmm8_combine_f16_kernel<<<grdRow, blk, 0, stream>>>(row_ptr, sedges, HA,
                                                                 nullptr, 1, nullptr, 1,
                                                                 u4, it4, c1, c0, 0.0f, HB);
            // e2 = th1*spmm(e1) + th2*e1 - th3*e0 -> HC
            spmm8_combine_f16_kernel<<<grdRow, blk, 0, stream>>>(row_ptr, sedges, HB,
                                                                 HB, 0, nullptr, 1,
                                                                 u4, it4, th1[2], th2[2], th3[2],
                                                                 HC);
            // e3 + band-stop + band-pass fused    -> out
            spmm8_final_kernel<<<grdRow, blk, 0, stream>>>(row_ptr, sedges, HC, HB, HC,
                                                           u4, it4, th1[3], th2[3], th3[3],
                                                           (float4*)out);
        } else {
            // ---- exact fp32-gather path (legacy accumulate-into-out) ----
            concat_init_kernel<<<grd4, blk, 0, stream>>>(u4, it4, (float4*)W0, nullptr, (float4*)out);
            spmm_combine_kernel<<<grdRow, blk, 0, stream>>>(row_ptr, sedges, W0, W0, W0,
                                                            c1, c0, 0.0f, W1, out);
            spmm_combine_kernel<<<grdRow, blk, 0, stream>>>(row_ptr, sedges, W1, W1, W0,
                                                            th1[2], th2[2], th3[2], W2, out);
            spmm_combine_kernel<<<grdRow, blk, 0, stream>>>(row_ptr, sedges, W2, W2, W1,
                                                            th1[3], th2[3], th3[3], W0, out);
            finalize_kernel<<<grdE, blk, 0, stream>>>(user_emb, item_emb, out);
        }
    } else {
        // ---- fallback: atomic path ----
        long long spmm_threads = (long long)NE * 64;
        dim3 grdS((unsigned)((spmm_threads + 255) / 256));
        concat_init_kernel<<<grd4, blk, 0, stream>>>(u4, it4, (float4*)W0, nullptr, (float4*)out);
        hipMemsetAsync(W1, 0, nbuf * sizeof(float), stream);
        spmm_atomic_kernel<<<grdS, blk, 0, stream>>>(rows, cols, vals, W0, W1);
        combine3_kernel<<<grdE, blk, 0, stream>>>(W1, W0, W0, c1, c0, 0.0f, out);
        hipMemsetAsync(W2, 0, nbuf * sizeof(float), stream);
        spmm_atomic_kernel<<<grdS, blk, 0, stream>>>(rows, cols, vals, W1, W2);
        combine3_kernel<<<grdE, blk, 0, stream>>>(W2, W1, W0, th1[2], th2[2], th3[2], out);
        hipMemsetAsync(W0, 0, nbuf * sizeof(float), stream);
        spmm_atomic_kernel<<<grdS, blk, 0, stream>>>(rows, cols, vals, W2, W0);
        combine3_kernel<<<grdE, blk, 0, stream>>>(W0, W2, W1, th1[3], th2[3], th3[3], out);
        finalize_kernel<<<grdE, blk, 0, stream>>>(user_emb, item_emb, out);
    }
}

// Round 14
// 400.242 us; speedup vs baseline: 1.1086x; 1.1086x over previous
//
#include <hip/hip_runtime.h>
#include <hip/hip_fp16.h>
#include <cmath>
#include <cstdint>

#define NU 100000
#define NI 50000
#define NALL 150000
#define DIM 64
#define NE 4800000

#define BSH 7                 // bucket = row >> 7  (128 rows/bucket)
#define BROWS 128
#define NBUCK ((NALL + BROWS - 1) / BROWS)   // 1172
#define SBT 512               // sort-kernel block threads
#define EPT 8                 // edges per thread (512 * 8 = 4096 per block)
#define CHUNK (SBT * EPT)     // 4096 edges per binning block
#define COLMASK 0x3FFFF       // 18 bits, NALL < 2^18
#define CAP 8192              // fixed per-bucket capacity in tmp (mean 4096, 64 sigma)
#define BCAP 4608             // staged-sort capacity (mean + 8 sigma)
#define SPT 9                 // staged regs per thread in bucket_sort (512*9=4608)

// ---------------- edge sort: fixed-capacity buckets (no pre-histogram) ----------------

// Exclusive scan of bfill[NBUCK] -> bptr[NBUCK+1] (runs AFTER binned_scatter).
__global__ void bucket_scan_kernel(const int* __restrict__ bfill, int* __restrict__ bptr) {
    __shared__ int s[1024];
    int t = threadIdx.x;
    const int chunk = (NBUCK + 1023) / 1024;   // 2
    int lo = t * chunk, hi = lo + chunk;
    if (hi > NBUCK) hi = NBUCK;
    int sum = 0;
    for (int i = lo; i < hi; ++i) sum += bfill[i];
    s[t] = sum;
    __syncthreads();
    for (int off = 1; off < 1024; off <<= 1) {
        int v = (t >= off) ? s[t - off] : 0;
        __syncthreads();
        s[t] += v;
        __syncthreads();
    }
    int run = s[t] - sum;
    for (int i = lo; i < hi; ++i) { bptr[i] = run; run += bfill[i]; }
    if (t == 1023) bptr[NBUCK] = s[1023];
}

// LDS-presorted binned scatter into fixed-capacity bucket regions of tmp.
__global__ __launch_bounds__(SBT, 6) void binned_scatter_kernel(
        const int* __restrict__ rows, const int* __restrict__ cols,
        const float* __restrict__ vals,
        int* __restrict__ bfill, int2* __restrict__ tmp) {
    __shared__ int2 eLDS[CHUNK];             // 32 KB
    __shared__ unsigned short bLDS[CHUNK];   // 8 KB bucket-id sidecar
    __shared__ int lcnt[NBUCK];              // ranks, then writeout delta
    __shared__ int lofs[NBUCK + 1];
    __shared__ int psum[SBT];
    int t = threadIdx.x;
    int base = blockIdx.x * CHUNK;
    int cnt = NE - base; if (cnt > CHUNK) cnt = CHUNK;
    for (int i = t; i < NBUCK; i += SBT) lcnt[i] = 0;
    __syncthreads();
    int2 ed[EPT]; int mcb[EPT]; int mrk[EPT];
    #pragma unroll
    for (int k = 0; k < EPT; k++) {
        int p = t + k * SBT;
        mcb[k] = -1;
        if (p < cnt) {
            int e = base + p;
            int r = rows[e];
            int cb = r >> BSH;
            mcb[k] = cb;
            mrk[k] = atomicAdd(&lcnt[cb], 1);
            ed[k] = make_int2(((r & (BROWS - 1)) << 18) | cols[e], __float_as_int(vals[e]));
        }
    }
    __syncthreads();
    const int cpt = (NBUCK + SBT - 1) / SBT;   // 3
    int lo = t * cpt, hi = lo + cpt;
    if (lo > NBUCK) lo = NBUCK;
    if (hi > NBUCK) hi = NBUCK;
    int s = 0;
    for (int i = lo; i < hi; ++i) s += lcnt[i];
    psum[t] = s;
    __syncthreads();
    for (int off = 1; off < SBT; off <<= 1) {
        int v = (t >= off) ? psum[t - off] : 0;
        __syncthreads();
        psum[t] += v;
        __syncthreads();
    }
    int run = psum[t] - s;
    for (int i = lo; i < hi; ++i) { lofs[i] = run; run += lcnt[i]; }
    if (t == SBT - 1) lofs[NBUCK] = cnt;
    __syncthreads();
    // reserve per-bucket space at fixed base i*CAP; lcnt := dest_base - local_base
    for (int i = t; i < NBUCK; i += SBT) {
        int c = lcnt[i];
        int g = c ? atomicAdd(&bfill[i], c) : 0;
        lcnt[i] = i * CAP + g - lofs[i];
    }
    #pragma unroll
    for (int k = 0; k < EPT; k++)
        if (mcb[k] >= 0) {
            int pos = lofs[mcb[k]] + mrk[k];
            eLDS[pos] = ed[k];
            bLDS[pos] = (unsigned short)mcb[k];
        }
    __syncthreads();
    for (int p = t; p < cnt; p += SBT)
        tmp[lcnt[bLDS[p]] + p] = eLDS[p];
}

// Staged within-bucket counting sort; reads fixed-capacity tmp region, writes
// compact sedges at bptr[b]; emits row_ptr.
__global__ __launch_bounds__(SBT, 6) void bucket_sort_kernel(
        const int* __restrict__ bptr, const int2* __restrict__ tmp,
        int2* __restrict__ sedges, int* __restrict__ row_ptr) {
    __shared__ int2 eLDS[BCAP];           // 36.9 KB
    __shared__ int h[BROWS], sc[BROWS], f[BROWS];
    int b = blockIdx.x, t = threadIdx.x;
    int s0 = bptr[b], s1 = bptr[b + 1];
    int cnt = s1 - s0;
    const int2* src = tmp + (size_t)b * CAP;
    if (t < BROWS) { h[t] = 0; f[t] = 0; }
    if (b == NBUCK - 1 && t == 0) row_ptr[NALL] = s1;
    __syncthreads();
    if (cnt <= BCAP) {
        int2 ed[SPT]; int mrl[SPT]; int mrk[SPT];
        #pragma unroll
        for (int k = 0; k < SPT; k++) {
            int p = t + k * SBT;
            mrl[k] = -1;
            if (p < cnt) {
                int2 E = src[p];
                int rl = E.x >> 18;
                mrl[k] = rl;
                mrk[k] = atomicAdd(&h[rl], 1);
                ed[k] = E;
            }
        }
        __syncthreads();
        if (t < BROWS) sc[t] = h[t];
        __syncthreads();
        for (int off = 1; off < BROWS; off <<= 1) {
            int v = 0;
            if (t < BROWS && t >= off) v = sc[t - off];
            __syncthreads();
            if (t < BROWS) sc[t] += v;
            __syncthreads();
        }
        if (t < BROWS) {
            int row = b * BROWS + t;
            if (row < NALL) row_ptr[row] = s0 + sc[t] - h[t];
        }
        __syncthreads();
        #pragma unroll
        for (int k = 0; k < SPT; k++)
            if (mrl[k] >= 0) eLDS[sc[mrl[k]] - h[mrl[k]] + mrk[k]] = ed[k];
        __syncthreads();
        for (int p = t; p < cnt; p += SBT) sedges[s0 + p] = eLDS[p];
    } else {
        for (int i = t; i < cnt; i += SBT) atomicAdd(&h[src[i].x >> 18], 1);
        __syncthreads();
        if (t < BROWS) sc[t] = h[t];
        __syncthreads();
        for (int off = 1; off < BROWS; off <<= 1) {
            int v = 0;
            if (t < BROWS && t >= off) v = sc[t - off];
            __syncthreads();
            if (t < BROWS) sc[t] += v;
            __syncthreads();
        }
        if (t < BROWS) {
            int row = b * BROWS + t;
            if (row < NALL) row_ptr[row] = s0 + sc[t] - h[t];
        }
        __syncthreads();
        for (int i = t; i < cnt; i += SBT) {
            int2 E = src[i];
            int rl = E.x >> 18;
            int r = atomicAdd(&f[rl], 1);
            sedges[s0 + sc[rl] - h[rl] + r] = E;
        }
    }
}

// ---------------- embedding passes ----------------

__global__ void concat_init_kernel(const float4* __restrict__ u4, const float4* __restrict__ it4,
                                   float4* __restrict__ w0, uint2* __restrict__ w0h,
                                   float4* __restrict__ out4) {
    int idx = blockIdx.x * blockDim.x + threadIdx.x;
    const int total4 = NALL * 16;
    if (idx >= total4) return;
    const int nu4 = NU * 16;
    float4 v = (idx < nu4) ? u4[idx] : it4[idx - nu4];
    if (w0) w0[idx] = v;
    if (w0h) {
        __half2 a = __floats2half2_rn(v.x, v.y), b = __floats2half2_rn(v.z, v.w);
        w0h[idx] = make_uint2(*(unsigned*)&a, *(unsigned*)&b);
    }
    if (out4) {
        int row = idx >> 4, q = idx & 15;
        out4[(size_t)row * 32 + q] = v;
    }
}

// Mixed-precision FMA: acc(f32) += f16(lo/hi of x) * v(f32) in ONE VOP3P instruction.
#define FMAMIX_LO(a, x, s) asm("v_fma_mix_f32 %0, %1, %2, %0 op_sel:[0,0,0] op_sel_hi:[1,0,0]" : "+v"(a) : "v"(x), "v"(s))
#define FMAMIX_HI(a, x, s) asm("v_fma_mix_f32 %0, %1, %2, %0 op_sel:[1,0,0] op_sel_hi:[1,0,0]" : "+v"(a) : "v"(x), "v"(s))

__device__ __forceinline__ void fma_mix8(float* acc, uint4 p, float v) {
    FMAMIX_LO(acc[0], p.x, v); FMAMIX_HI(acc[1], p.x, v);
    FMAMIX_LO(acc[2], p.y, v); FMAMIX_HI(acc[3], p.y, v);
    FMAMIX_LO(acc[4], p.z, v); FMAMIX_HI(acc[5], p.z, v);
    FMAMIX_LO(acc[6], p.w, v); FMAMIX_HI(acc[7], p.w, v);
}

// float4 pair (dims [l8*8, l8*8+8)) of row `wid` from the concatenated fp32 inputs.
__device__ __forceinline__ void load_pair_e0(const float4* __restrict__ u4,
                                             const float4* __restrict__ it4,
                                             int wid, int l8, float4& a, float4& b) {
    const float4* q = (wid < NU) ? (u4 + (size_t)wid * 16 + l8 * 2)
                                 : (it4 + (size_t)(wid - NU) * 16 + l8 * 2);
    a = q[0]; b = q[1];
}

// same pair from an fp16 mirror (one uint4 = 8 halves).
__device__ __forceinline__ void load_pair_h(const __half* __restrict__ h,
                                            int wid, int l8, float4& a, float4& b) {
    uint4 p = ((const uint4*)h)[(size_t)wid * 8 + l8];
    __half2* hp = (__half2*)&p;
    float2 f0 = __half22float2(hp[0]);
    float2 f1 = __half22float2(hp[1]);
    float2 f2 = __half22float2(hp[2]);
    float2 f3 = __half22float2(hp[3]);
    a = make_float4(f0.x, f0.y, f1.x, f1.y);
    b = make_float4(f2.x, f2.y, f3.x, f3.y);
}

__device__ __forceinline__ uint4 pack_h8(float4 a, float4 b) {
    __half2 h0 = __floats2half2_rn(a.x, a.y);
    __half2 h1 = __floats2half2_rn(a.z, a.w);
    __half2 h2 = __floats2half2_rn(b.x, b.y);
    __half2 h3 = __floats2half2_rn(b.z, b.w);
    uint4 ph;
    ph.x = *(unsigned*)&h0; ph.y = *(unsigned*)&h1;
    ph.z = *(unsigned*)&h2; ph.w = *(unsigned*)&h3;
    return ph;
}

// Contiguous-4 edge blocks per 8-lane group; 4 gathers in flight; trailing vals
// zero-predicated. Reads ≤3 past row end hit next row (masked) or zeroed slack.
__device__ __forceinline__ void spmm_row_acc(const int* __restrict__ row_ptr,
                                             const int2* __restrict__ sedges,
                                             const uint4* __restrict__ xv,
                                             int wid, int g, int l8, float* acc) {
    int s = row_ptr[wid], e = row_ptr[wid + 1];
    for (int j = s + 4 * g; j < e; j += 32) {
        const int4* p2 = (const int4*)(sedges + j);
        int4 eA = p2[0];
        int4 eB = p2[1];
        uint4 q0 = xv[(size_t)(eA.x & COLMASK) * 8 + l8];
        uint4 q1 = xv[(size_t)(eA.z & COLMASK) * 8 + l8];
        uint4 q2 = xv[(size_t)(eB.x & COLMASK) * 8 + l8];
        uint4 q3 = xv[(size_t)(eB.z & COLMASK) * 8 + l8];
        float v0 = __int_as_float(eA.y);
        float v1 = (j + 1 < e) ? __int_as_float(eA.w) : 0.f;
        float v2 = (j + 2 < e) ? __int_as_float(eB.y) : 0.f;
        float v3 = (j + 3 < e) ? __int_as_float(eB.w) : 0.f;
        fma_mix8(acc, q0, v0);
        fma_mix8(acc, q1, v1);
        fma_mix8(acc, q2, v2);
        fma_mix8(acc, q3, v3);
    }
    #pragma unroll
    for (int off = 8; off < 64; off <<= 1) {
        #pragma unroll
        for (int j = 0; j < 8; j++) acc[j] += __shfl_xor(acc[j], off);
    }
}

// Passes 1..N-1: ek = t1*spmm(x) + t2*ekm1 - t3*ekm2; result lives ONLY as fp16 mirror.
__global__ __launch_bounds__(256) void spmm8_combine_f16_kernel(
        const int* __restrict__ row_ptr, const int2* __restrict__ sedges,
        const __half* __restrict__ xh,
        const __half* __restrict__ em1h, int em1_embed,
        const __half* __restrict__ em2h, int em2_embed,
        const float4* __restrict__ u4, const float4* __restrict__ it4,
        float t1, float t2, float t3,
        __half* __restrict__ ekh_out) {
    int wid = (blockIdx.x * blockDim.x + threadIdx.x) >> 6;
    if (wid >= NALL) return;
    int lane = threadIdx.x & 63;
    int g = lane >> 3, l8 = lane & 7;
    float acc[8];
    #pragma unroll
    for (int j = 0; j < 8; j++) acc[j] = 0.f;
    spmm_row_acc(row_ptr, sedges, (const uint4*)xh, wid, g, l8, acc);
    if (g == 0) {
        float4 ea, eb;
        ea.x = t1 * acc[0]; ea.y = t1 * acc[1]; ea.z = t1 * acc[2]; ea.w = t1 * acc[3];
        eb.x = t1 * acc[4]; eb.y = t1 * acc[5]; eb.z = t1 * acc[6]; eb.w = t1 * acc[7];
        if (t2 != 0.f) {
            float4 m1a, m1b;
            if (em1_embed) load_pair_e0(u4, it4, wid, l8, m1a, m1b);
            else           load_pair_h(em1h, wid, l8, m1a, m1b);
            ea.x += t2 * m1a.x; ea.y += t2 * m1a.y; ea.z += t2 * m1a.z; ea.w += t2 * m1a.w;
            eb.x += t2 * m1b.x; eb.y += t2 * m1b.y; eb.z += t2 * m1b.z; eb.w += t2 * m1b.w;
        }
        if (t3 != 0.f) {
            float4 m2a, m2b;
            if (em2_embed) load_pair_e0(u4, it4, wid, l8, m2a, m2b);
            else           load_pair_h(em2h, wid, l8, m2a, m2b);
            ea.x -= t3 * m2a.x; ea.y -= t3 * m2a.y; ea.z -= t3 * m2a.z; ea.w -= t3 * m2a.w;
            eb.x -= t3 * m2b.x; eb.y -= t3 * m2b.y; eb.z -= t3 * m2b.z; eb.w -= t3 * m2b.w;
        }
        ((uint4*)ekh_out)[(size_t)wid * 8 + l8] = pack_h8(ea, eb);
    }
}

// Final pass fused with finalize: e3 = t1*spmm(e2) + t2*e2 - t3*e1;
// bs = (e0+e1+e2+e3)/4; bp = tanh(0.1*e0 - bs). e0 from fp32 inputs; e1,e2 fp16.
__global__ __launch_bounds__(256) void spmm8_final_kernel(
        const int* __restrict__ row_ptr, const int2* __restrict__ sedges,
        const __half* __restrict__ xh,
        const __half* __restrict__ e1h, const __half* __restrict__ e2h,
        const float4* __restrict__ u4, const float4* __restrict__ it4,
        float t1, float t2, float t3,
        float4* __restrict__ out4) {
    int wid = (blockIdx.x * blockDim.x + threadIdx.x) >> 6;
    if (wid >= NALL) return;
    int lane = threadIdx.x & 63;
    int g = lane >> 3, l8 = lane & 7;
    float acc[8];
    #pragma unroll
    for (int j = 0; j < 8; j++) acc[j] = 0.f;
    spmm_row_acc(row_ptr, sedges, (const uint4*)xh, wid, g, l8, acc);
    if (g == 0) {
        float4 e0a, e0b, e1a, e1b, e2a, e2b;
        load_pair_e0(u4, it4, wid, l8, e0a, e0b);
        load_pair_h(e1h, wid, l8, e1a, e1b);
        load_pair_h(e2h, wid, l8, e2a, e2b);
        float4 e3a, e3b;
        e3a.x = t1 * acc[0] + t2 * e2a.x - t3 * e1a.x;
        e3a.y = t1 * acc[1] + t2 * e2a.y - t3 * e1a.y;
        e3a.z = t1 * acc[2] + t2 * e2a.z - t3 * e1a.z;
        e3a.w = t1 * acc[3] + t2 * e2a.w - t3 * e1a.w;
        e3b.x = t1 * acc[4] + t2 * e2b.x - t3 * e1b.x;
        e3b.y = t1 * acc[5] + t2 * e2b.y - t3 * e1b.y;
        e3b.z = t1 * acc[6] + t2 * e2b.z - t3 * e1b.z;
        e3b.w = t1 * acc[7] + t2 * e2b.w - t3 * e1b.w;
        float4 bsa, bsb, bpa, bpb;
        bsa.x = 0.25f * (e0a.x + e1a.x + e2a.x + e3a.x);
        bsa.y = 0.25f * (e0a.y + e1a.y + e2a.y + e3a.y);
        bsa.z = 0.25f * (e0a.z + e1a.z + e2a.z + e3a.z);
        bsa.w = 0.25f * (e0a.w + e1a.w + e2a.w + e3a.w);
        bsb.x = 0.25f * (e0b.x + e1b.x + e2b.x + e3b.x);
        bsb.y = 0.25f * (e0b.y + e1b.y + e2b.y + e3b.y);
        bsb.z = 0.25f * (e0b.z + e1b.z + e2b.z + e3b.z);
        bsb.w = 0.25f * (e0b.w + e1b.w + e2b.w + e3b.w);
        bpa.x = tanhf(0.1f * e0a.x - bsa.x);
        bpa.y = tanhf(0.1f * e0a.y - bsa.y);
        bpa.z = tanhf(0.1f * e0a.z - bsa.z);
        bpa.w = tanhf(0.1f * e0a.w - bsa.w);
        bpb.x = tanhf(0.1f * e0b.x - bsb.x);
        bpb.y = tanhf(0.1f * e0b.y - bsb.y);
        bpb.z = tanhf(0.1f * e0b.z - bsb.z);
        bpb.w = tanhf(0.1f * e0b.w - bsb.w);
        size_t ob = (size_t)wid * 32 + l8 * 2;
        out4[ob] = bsa;
        out4[ob + 1] = bsb;
        out4[ob + 16] = bpa;
        out4[ob + 17] = bpb;
    }
}

// ---------------- fallback kernels (ws-constrained paths) ----------------

__global__ void spmm_combine_kernel(const int* __restrict__ row_ptr,
                                    const int2* __restrict__ sedges,
                                    const float* __restrict__ x,
                                    const float* __restrict__ ekm1,
                                    const float* __restrict__ ekm2,
                                    float t1, float t2, float t3,
                                    float* __restrict__ ek_out,
                                    float* __restrict__ out) {
    int wid = (blockIdx.x * blockDim.x + threadIdx.x) >> 6;
    if (wid >= NALL) return;
    int lane = threadIdx.x & 63;
    int s = row_ptr[wid], e = row_ptr[wid + 1];
    float acc = 0.f;
    int i = s;
    for (; i + 4 <= e; i += 4) {
        int2 ea = sedges[i], eb = sedges[i + 1], ec = sedges[i + 2], ed = sedges[i + 3];
        acc += __int_as_float(ea.y) * x[(size_t)(ea.x & COLMASK) * DIM + lane];
        acc += __int_as_float(eb.y) * x[(size_t)(eb.x & COLMASK) * DIM + lane];
        acc += __int_as_float(ec.y) * x[(size_t)(ec.x & COLMASK) * DIM + lane];
        acc += __int_as_float(ed.y) * x[(size_t)(ed.x & COLMASK) * DIM + lane];
    }
    for (; i < e; ++i) {
        int2 ed = sedges[i];
        acc += __int_as_float(ed.y) * x[(size_t)(ed.x & COLMASK) * DIM + lane];
    }
    size_t o = (size_t)wid * DIM + lane;
    float ek = t1 * acc + t2 * ekm1[o] - t3 * ekm2[o];
    ek_out[o] = ek;
    out[(size_t)wid * 128 + lane] += ek;
}

__global__ void finalize_kernel(const float* __restrict__ u, const float* __restrict__ it,
                                float* __restrict__ out) {
    int idx = blockIdx.x * blockDim.x + threadIdx.x;
    const int total = NALL * DIM;
    if (idx >= total) return;
    const int nue = NU * DIM;
    float v = (idx < nue) ? u[idx] : it[idx - nue];
    int row = idx >> 6, d = idx & 63;
    size_t o = (size_t)row * 128 + d;
    float bs = out[o] * 0.25f;
    float bp = tanhf(0.1f * v - bs);
    out[o] = bs;
    out[o + DIM] = bp;
}

__global__ void spmm_atomic_kernel(const int* __restrict__ rows, const int* __restrict__ cols,
                                   const float* __restrict__ vals, const float* __restrict__ x,
                                   float* __restrict__ y) {
    int gid = blockIdx.x * blockDim.x + threadIdx.x;
    int e = gid >> 6;
    if (e >= NE) return;
    int lane = threadIdx.x & 63;
    atomicAdd(&y[(size_t)rows[e] * DIM + lane], vals[e] * x[(size_t)cols[e] * DIM + lane]);
}

__global__ void combine3_kernel(float* __restrict__ t, const float* __restrict__ ekm1,
                                const float* __restrict__ ekm2, float t1, float t2, float t3,
                                float* __restrict__ out) {
    int idx = blockIdx.x * blockDim.x + threadIdx.x;
    const int total = NALL * DIM;
    if (idx >= total) return;
    float ek = t1 * t[idx] + t2 * ekm1[idx] - t3 * ekm2[idx];
    t[idx] = ek;
    int row = idx >> 6, d = idx & 63;
    out[(size_t)row * 128 + d] += ek;
}

// ---------------- launch ----------------

extern "C" void kernel_launch(void* const* d_in, const int* in_sizes, int n_in,
                              void* d_out, int out_size, void* d_ws, size_t ws_size,
                              hipStream_t stream) {
    const float* user_emb = (const float*)d_in[0];
    const float* item_emb = (const float*)d_in[1];
    const int*   rows     = (const int*)d_in[2];
    const int*   cols     = (const int*)d_in[3];
    const float* vals     = (const float*)d_in[4];
    float* out = (float*)d_out;

    const size_t nbuf = (size_t)NALL * DIM;            // 9.6M elements
    float* W0 = (float*)d_ws;
    float* W1 = W0 + nbuf;
    float* W2 = W1 + nbuf;
    int2*  tmp     = (int2*)W0;                        // fixed-cap buckets: NBUCK*CAP*8B = 76.8MB
                                                       // (fits W0..W2 = 115MB; dead before propagation)
    int2*  sedges  = (int2*)(W2 + nbuf);               // NE * 8 B (+ 4-edge zero slack)
    int*   row_ptr = (int*)(sedges + NE + 4);          // NALL+1
    int*   bptr    = row_ptr + (NALL + 1);             // NBUCK+1
    int*   bfill   = bptr + (NBUCK + 1);               // NBUCK
    char*  pHA     = (char*)(bfill + NBUCK);
    pHA = (char*)(((uintptr_t)pHA + 255) & ~(uintptr_t)255);   // 256B-align mirrors
    __half* HA     = (__half*)pHA;                     // fp16 e0 mirror
    __half* HB     = HA + nbuf;                        // fp16 e1 mirror
    __half* HC     = HB + nbuf;                        // fp16 e2 mirror
    size_t need_basic = (size_t)((char*)HA - (char*)d_ws);
    size_t need_full  = (size_t)((char*)(HC + nbuf) - (char*)d_ws);

    // Jacobi coefficients (A=B=1 here, computed generically)
    const double A = 1.0, B = 1.0, ab = A + B;
    float c0 = (float)((A - B) / 2.0);
    float c1 = (float)((A + B) / 2.0);
    float th1[4], th2[4], th3[4];
    for (int k = 2; k <= 3; k++) {
        th1[k] = (float)((2.0*k+ab)*(2.0*k+ab-1.0)/((k+ab)*2.0*k));
        th2[k] = (float)((2.0*k+ab-1.0)*(A*A-B*B)/((2.0*k+ab-2.0)*(k+ab)*2.0*k));
        th3[k] = (float)((k+A-1.0)*(k+B-1.0)*(2.0*k+ab)/(k*(ab+k)*(2.0*k+ab-2.0)));
    }

    const int total = NALL * DIM;
    const int total4 = NALL * 16;
    dim3 blk(256);
    dim3 sblk(SBT);
    dim3 grdE((total + 255) / 256);
    dim3 grd4((total4 + 255) / 256);
    dim3 grdBin((NE + CHUNK - 1) / CHUNK);             // 1172
    dim3 grdBuck(NBUCK);                               // 1172
    dim3 grdRow((NALL * 64 + 255) / 256);              // wave-per-row

    const float4* u4  = (const float4*)user_emb;
    const float4* it4 = (const float4*)item_emb;

    if (ws_size >= need_basic) {
        // ---- edge sort (no pre-histogram: fixed-capacity buckets, post-scan) ----
        hipMemsetAsync(bfill, 0, NBUCK * sizeof(int), stream);
        hipMemsetAsync(sedges + NE, 0, 4 * sizeof(int2), stream);   // gather-slack
        binned_scatter_kernel<<<grdBin, sblk, 0, stream>>>(rows, cols, vals, bfill, tmp);
        bucket_scan_kernel<<<1, 1024, 0, stream>>>(bfill, bptr);
        bucket_sort_kernel<<<grdBuck, sblk, 0, stream>>>(bptr, tmp, sedges, row_ptr);

        if (ws_size >= need_full) {
            // ---- fp16-mirror-only pipeline ----
            concat_init_kernel<<<grd4, blk, 0, stream>>>(u4, it4, nullptr, (uint2*)HA, nullptr);
            // e1 = c1*spmm(e0) + c0*e0            -> HB
            spmm8_combine_f16_kernel<<<grdRow, blk, 0, stream>>>(row_ptr, sedges, HA,
                                                                 nullptr, 1, nullptr, 1,
                                                                 u4, it4, c1, c0, 0.0f, HB);
            // e2 = th1*spmm(e1) + th2*e1 - th3*e0 -> HC
            spmm8_combine_f16_kernel<<<grdRow, blk, 0, stream>>>(row_ptr, sedges, HB,
                                                                 HB, 0, nullptr, 1,
                                                                 u4, it4, th1[2], th2[2], th3[2],
                                                                 HC);
            // e3 + band-stop + band-pass fused    -> out
            spmm8_final_kernel<<<grdRow, blk, 0, stream>>>(row_ptr, sedges, HC, HB, HC,
                                                           u4, it4, th1[3], th2[3], th3[3],
                                                           (float4*)out);
        } else {
            // ---- exact fp32-gather path (legacy accumulate-into-out) ----
            concat_init_kernel<<<grd4, blk, 0, stream>>>(u4, it4, (float4*)W0, nullptr, (float4*)out);
            spmm_combine_kernel<<<grdRow, blk, 0, stream>>>(row_ptr, sedges, W0, W0, W0,
                                                            c1, c0, 0.0f, W1, out);
            spmm_combine_kernel<<<grdRow, blk, 0, stream>>>(row_ptr, sedges, W1, W1, W0,
                                                            th1[2], th2[2], th3[2], W2, out);
            spmm_combine_kernel<<<grdRow, blk, 0, stream>>>(row_ptr, sedges, W2, W2, W1,
                                                            th1[3], th2[3], th3[3], W0, out);
            finalize_kernel<<<grdE, blk, 0, stream>>>(user_emb, item_emb, out);
        }
    } else {
        // ---- fallback: atomic path ----
        long long spmm_threads = (long long)NE * 64;
        dim3 grdS((unsigned)((spmm_threads + 255) / 256));
        concat_init_kernel<<<grd4, blk, 0, stream>>>(u4, it4, (float4*)W0, nullptr, (float4*)out);
        hipMemsetAsync(W1, 0, nbuf * sizeof(float), stream);
        spmm_atomic_kernel<<<grdS, blk, 0, stream>>>(rows, cols, vals, W0, W1);
        combine3_kernel<<<grdE, blk, 0, stream>>>(W1, W0, W0, c1, c0, 0.0f, out);
        hipMemsetAsync(W2, 0, nbuf * sizeof(float), stream);
        spmm_atomic_kernel<<<grdS, blk, 0, stream>>>(rows, cols, vals, W1, W2);
        combine3_kernel<<<grdE, blk, 0, stream>>>(W2, W1, W0, th1[2], th2[2], th3[2], out);
        hipMemsetAsync(W0, 0, nbuf * sizeof(float), stream);
        spmm_atomic_kernel<<<grdS, blk, 0, stream>>>(rows, cols, vals, W2, W0);
        combine3_kernel<<<grdE, blk, 0, stream>>>(W0, W2, W1, th1[3], th2[3], th3[3], out);
        finalize_kernel<<<grdE, blk, 0, stream>>>(user_emb, item_emb, out);
    }
}